// Round 2
// baseline (188.701 us; speedup 1.0000x reference)
//
#include <hip/hip_runtime.h>
#include <cstdint>

typedef __attribute__((ext_vector_type(8))) short short8;     // 8 bf16 (4 VGPRs)
typedef __attribute__((ext_vector_type(4))) float floatx4;
typedef __attribute__((ext_vector_type(2))) unsigned int uintx2;
typedef __attribute__((ext_vector_type(4))) unsigned int uintx4;

#define CS 18                    // LDS cell stride in words (16 kpair + 2 pad): conflict-free frag reads
#define A_WORDS (8 * 16 * CS)    // 8 h-rows x 16 w cells                  = 2304 words
#define B_ROWS  13               // 12 halo rows + 1 dump row for idle staging threads
#define B_WORDS (B_ROWS * 24 * CS)  // 13 rows x 24 col cells              = 5616 words
// LDS total = 2*(A_WORDS+B_WORDS)*4 = 63360 B  -> 2 blocks/CU (124 KB of 160)

__device__ __forceinline__ uint32_t pack2(float a, float b) {
    uint32_t ua = __builtin_bit_cast(uint32_t, a);
    uint32_t ub = __builtin_bit_cast(uint32_t, b);
    ua = (ua + 0x7FFFu + ((ua >> 16) & 1u)) >> 16;   // RNE (verified prev session, absmax 0.5)
    ub = (ub + 0x7FFFu + ((ub >> 16) & 1u)) >> 16;
    return ua | (ub << 16);                           // lo = even channel, hi = odd channel
}

__device__ __forceinline__ short8 frag_ld(const uint32_t* p) {
    uintx2 lo = *(const uintx2*)p;        // ds_read_b64 (cells 8B-aligned: CS*4=72 ≡ 0 mod 8)
    uintx2 hi = *(const uintx2*)(p + 2);
    uintx4 v = {lo.x, lo.y, hi.x, hi.y};
    return __builtin_bit_cast(short8, v);
}

// LDS-only barrier: __syncthreads() would emit s_waitcnt vmcnt(0) before s_barrier,
// draining our prefetch loads chip-wide every chunk (the m97 burst-drain stall).
// We only need LDS writes visible across the wavegroup -> lgkmcnt(0) + s_barrier.
// In-flight global loads target private VGPRs; the compiler inserts progressive
// vmcnt(k) waits at their uses in packall(), AFTER the compute phase.
__device__ __forceinline__ void barrier_lgkm() {
    asm volatile("s_waitcnt lgkmcnt(0)\n\ts_barrier" ::: "memory");
}

// out[b, di*9+dj, h, w] = sum_c f1[b,c,h,w] * f2[b,c,h+di-4,w+dj-4]  (zero-padded)
// Structure: tile 8h x 16w, di split 5/4 across block pairs, 2 blocks/CU,
// double-buffered LDS, register prefetch, ONE lgkm-only barrier per chunk.
__global__ __launch_bounds__(512, 4)
void corr_kernel(const float* __restrict__ f1, const float* __restrict__ f2,
                 float* __restrict__ out) {
    __shared__ uint32_t ldsA[2 * A_WORDS];
    __shared__ uint32_t ldsB[2 * B_WORDS];

    const int tid  = threadIdx.x;
    const int lane = tid & 63;
    const int wh   = tid >> 6;        // wave id == h sub-row (0..7)
    const int n15  = lane & 15;
    const int q    = lane >> 4;

    const int bid    = blockIdx.x;
    const int b      = bid & 7;         // batch in low bits: XCD (bid%8) partitioned by batch
    const int dihalf = (bid >> 3) & 1;  // di group: 0 -> di 0..4, 1 -> di 5..8
    const int ht     = (bid >> 4) & 7;  // h tile -> h0 = 8*ht
    const int wt     = bid >> 7;        // w tile (0..7) -> w0 = 16*wt

    const int w0 = wt * 16;
    const int h0 = ht * 8;
    const int h  = h0 + wh;

    const int diN    = dihalf ? 4 : 5;         // block-uniform
    const int diBase = dihalf * 5;
    const int ghBase = dihalf ? (h0 + 1) : (h0 - 4);  // f2 row of LDS B row 0

    const float* f1b = f1 + (size_t)b * 256 * 8192;
    const float* f2b = f2 + (size_t)b * 256 * 8192;

    // ---- A staging: 512 tasks, exactly 1/thread (always in-bounds)
    const int aw4 = tid & 3, akp = (tid >> 2) & 15, arow = tid >> 6;
    int aOffG = (2 * akp) * 8192 + (h0 + arow) * 128 + (w0 + 4 * aw4);  // element offset, chunk 0
    const int aLds = (arow * 16 + 4 * aw4) * CS + akp;

    // ---- B staging: 12 rows x 6 w4-groups x 16 kp = 1152 tasks; 3 rounds of 512
    //      (round 2: threads >= 128 are idle -> write zeros into dump row 12)
    int bOffG[3];
    int bLds[3];
    uint32_t bMask[3];
#pragma unroll
    for (int s = 0; s < 3; ++s) {
        int t = tid + 512 * s;
        int w4 = t % 6;
        int r2 = t / 6;
        int kp = r2 & 15, row = r2 >> 4;
        int gh = ghBase + row;
        int gw = w0 - 4 + 4 * w4;                 // vec4 fully in or fully out (w0 % 16 == 0)
        bool live = (t < 1152);
        bool inb  = live && ((unsigned)gh < 64u) && ((unsigned)gw < 128u);
        bOffG[s] = inb ? ((2 * kp) * 8192 + gh * 128 + gw) : 0;
        bLds[s]  = live ? ((row * 24 + 4 * w4) * CS + kp)
                        : ((12 * 24 + (tid & 7)) * CS);   // dump row, harmless zeros
        bMask[s] = inb ? 0xFFFFFFFFu : 0u;
    }

    floatx4 acc[5][2];
#pragma unroll
    for (int dl = 0; dl < 5; ++dl)
#pragma unroll
        for (int t = 0; t < 2; ++t)
            acc[dl][t] = (floatx4){0.f, 0.f, 0.f, 0.f};

    floatx4 rA[2], rB[3][2];
    uint32_t pkA[4], pkB[12];

    auto issue = [&]() {   // non-blocking global loads for the next chunk (32 ch = 16 kpairs)
        rA[0] = *(const floatx4*)(f1b + aOffG);
        rA[1] = *(const floatx4*)(f1b + aOffG + 8192);
        aOffG += 32 * 8192;
#pragma unroll
        for (int s = 0; s < 3; ++s) {
            rB[s][0] = *(const floatx4*)(f2b + bOffG[s]);
            rB[s][1] = *(const floatx4*)(f2b + bOffG[s] + 8192);
            bOffG[s] += 32 * 8192;
        }
    };
    auto packall = [&]() {
#pragma unroll
        for (int i = 0; i < 4; ++i)
            pkA[i] = pack2(rA[0][i], rA[1][i]);
#pragma unroll
        for (int s = 0; s < 3; ++s)
#pragma unroll
            for (int i = 0; i < 4; ++i)
                pkB[4 * s + i] = pack2(rB[s][0][i], rB[s][1][i]) & bMask[s];
    };

    issue();      // chunk 0
    packall();

    for (int ch = 0; ch < 8; ++ch) {
        uint32_t* bufA = ldsA + (ch & 1) * A_WORDS;
        uint32_t* bufB = ldsB + (ch & 1) * B_WORDS;

        // write current chunk's packed words
#pragma unroll
        for (int i = 0; i < 4; ++i)
            bufA[aLds + i * CS] = pkA[i];
#pragma unroll
        for (int s = 0; s < 3; ++s)
#pragma unroll
            for (int i = 0; i < 4; ++i)
                bufB[bLds[s] + i * CS] = pkB[4 * s + i];

        if (ch < 7) issue();          // next chunk's loads: genuinely in flight now
        barrier_lgkm();               // LDS visible; vmcnt NOT drained (vs __syncthreads)

        const uint32_t* pa = bufA + (wh * 16 + n15) * CS + 4 * q;
        short8 a0 = frag_ld(pa);                       // m = w 0..15
        const uint32_t* pb = bufB + (wh * 24 + n15) * CS + 4 * q;
#pragma unroll
        for (int dl = 0; dl < 5; ++dl) {
            if (dl < diN) {                            // uniform branch (set1 skips dl=4)
                const uint32_t* p = pb + dl * (24 * CS);
                short8 b0 = frag_ld(p);                // B cols cb = 0..15  (f2 w = w0-4+cb)
                short8 b1 = frag_ld(p + 8 * CS);       // B cols cb = 8..23 (overlap; dedupe in epilogue)
                acc[dl][0] = __builtin_amdgcn_mfma_f32_16x16x32_bf16(a0, b0, acc[dl][0], 0, 0, 0);
                acc[dl][1] = __builtin_amdgcn_mfma_f32_16x16x32_bf16(a0, b1, acc[dl][1], 0, 0, 0);
            }
        }
        if (ch < 7) packall();        // vmcnt waits land HERE (after compute), not at barrier
        // single barrier/chunk: buffer reuse at ch+2 is ordered by the ch+1 barrier
        // (s_barrier execution semantics unchanged by the lgkm-only wait)
    }

    // ---- epilogue: band extraction. D[m'=4q+r][n'=n15]; tile t at col offset 8t:
    // cb = 8t + n', dj = cb - m', keep 0..8; t1 only stores cb >= 16 (dedupe of overlap cols 8..15)
    const size_t base = ((size_t)b * 81) * 8192 + (size_t)h * 128 + w0;
#pragma unroll
    for (int dl = 0; dl < 5; ++dl) {
        if (dl < diN) {
            const int dio = diBase + dl;
#pragma unroll
            for (int t = 0; t < 2; ++t) {
#pragma unroll
                for (int r = 0; r < 4; ++r) {
                    int mp = 4 * q + r;
                    int dj = t * 8 + n15 - mp;
                    if (dj >= 0 && dj <= 8 && (t == 0 || n15 >= 8)) {
                        out[base + (size_t)(dio * 9 + dj) * 8192 + mp] = acc[dl][t][r];
                    }
                }
            }
        }
    }
}

extern "C" void kernel_launch(void* const* d_in, const int* in_sizes, int n_in,
                              void* d_out, int out_size, void* d_ws, size_t ws_size,
                              hipStream_t stream) {
    const float* f1 = (const float*)d_in[0];
    const float* f2 = (const float*)d_in[1];
    float* out = (float*)d_out;
    // grid: 8 batches (low bits -> XCD partition) x 2 di-halves x 8 h-tiles x 8 w-tiles = 1024
    // 2 blocks/CU resident (62 KB LDS, <=128 regs) -> 16 waves/CU
    corr_kernel<<<dim3(1024), dim3(512), 0, stream>>>(f1, f2, out);
}

// Round 3
// 188.518 us; speedup vs baseline: 1.0010x; 1.0010x over previous
//
#include <hip/hip_runtime.h>
#include <cstdint>

typedef __attribute__((ext_vector_type(8))) short short8;     // 8 bf16 (4 VGPRs)
typedef __attribute__((ext_vector_type(4))) float floatx4;
typedef __attribute__((ext_vector_type(2))) unsigned int uintx2;
typedef __attribute__((ext_vector_type(4))) unsigned int uintx4;

__device__ __forceinline__ uint32_t pack2(float a, float b) {
    uint32_t ua = __builtin_bit_cast(uint32_t, a);
    uint32_t ub = __builtin_bit_cast(uint32_t, b);
    ua = (ua + 0x7FFFu + ((ua >> 16) & 1u)) >> 16;   // RNE (verified, absmax 0.5)
    ub = (ub + 0x7FFFu + ((ub >> 16) & 1u)) >> 16;
    return ua | (ub << 16);                           // lo = even channel, hi = odd channel
}

// =====================================================================
// PASS 1: transpose f2 [8,256,64,128] f32 -> t2p [8][64][144][128] u32
// (bf16 kpair-packed, k-major, W padded by 4 each side: wp = w+4; pads zero)
// Plus a 4KB zero stripe at the end (OOB-row staging source for pass 2).
// =====================================================================
#define T2P_WORDS ((size_t)8 * 64 * 144 * 128)   // 9,437,184 words = 36 MiB
#define WS_NEED   (T2P_WORDS * 4 + 4096)

__global__ __launch_bounds__(256)
void transpose_f2(const float* __restrict__ f2, uint32_t* __restrict__ t2p) {
    __shared__ float t[64][33];                   // 64ch x 32w tile (+1 pad)
    const int tid = threadIdx.x;
    const int bid = blockIdx.x;                   // 8b x 64h x 4wt = 2048
    const int b = bid & 7, h = (bid >> 3) & 63, wt = bid >> 9;
    const int w0 = wt * 32;
    const float* f2b = f2 + (size_t)b * 256 * 8192 + (size_t)h * 128 + w0;
    uint32_t* t2row = t2p + ((size_t)(b * 64 + h) * 144 + (w0 + 4)) * 128;

    const int rw = tid & 31, rc8 = tid >> 5;      // read: w lane, ch-group (8 ch each)
    const int kpL = tid & 31, wg = tid >> 5;      // write: kp lane, w-group (4 w each)

    for (int cc = 0; cc < 4; ++cc) {              // 4 chunks of 64 channels
        if (cc) __syncthreads();
#pragma unroll
        for (int i = 0; i < 8; ++i)
            t[rc8 * 8 + i][rw] = f2b[(size_t)(cc * 64 + rc8 * 8 + i) * 8192 + rw];
        __syncthreads();
#pragma unroll
        for (int j = 0; j < 4; ++j) {
            int w = wg * 4 + j;
            t2row[(size_t)w * 128 + cc * 32 + kpL] = pack2(t[2 * kpL][w], t[2 * kpL + 1][w]);
        }
    }
    // zero pads (wp 0..3 and 132..143) and the zero stripe
    if (wt == 0) {
        uint32_t* p = t2p + ((size_t)(b * 64 + h) * 144) * 128;
        for (int idx = tid; idx < 512; idx += 256) p[idx] = 0;
    }
    if (wt == 3) {
        uint32_t* p = t2p + ((size_t)(b * 64 + h) * 144 + 132) * 128;
        for (int idx = tid; idx < 1536; idx += 256) p[idx] = 0;
    }
    if (bid == 0) {
        uint32_t* z = t2p + T2P_WORDS;
        for (int idx = tid; idx < 1024; idx += 256) z[idx] = 0;
    }
}

// =====================================================================
// PASS 2: out[b, di*9+dj, h, w] = sum_c f1[b,c,h,w]*f2[b,c,h+di-4,w+dj-4]
// Block = 8 waves = 8h x 16w tile, ALL 9 di (acc[9][2] = 72 VGPR).
// B: global_load_lds (16B) from t2p with source-side swizzle gd = g ^ ((c>>1)&3)
//    -> ds_read_b128 frags 2-way-conflict-free. LDS = 2 x 32KB dbuf = 64KB.
// A: wave-private -> direct-to-register f32 loads + RNE pack (no LDS, no barrier dep).
// Counted vmcnt(8): B stages drained at barrier, A loads stay in flight.
// =====================================================================
#define AS1 __attribute__((address_space(1)))
#define AS3 __attribute__((address_space(3)))

__device__ __forceinline__ void gld_lds16(const uint32_t* src, uint32_t* dst) {
    __builtin_amdgcn_global_load_lds((const AS1 void*)src, (AS3 void*)dst, 16, 0, 0);
}

__global__ __launch_bounds__(512, 4)
void corr2(const float* __restrict__ f1, const uint32_t* __restrict__ t2p,
           const uint32_t* __restrict__ wsZ, float* __restrict__ out) {
    __shared__ uint32_t ldsB[2 * 8192];           // 2 x [16 rows][32 c][16 words] = 64 KB

    const int tid  = threadIdx.x;
    const int lane = tid & 63;
    const int wh   = tid >> 6;                    // wave id == h sub-row
    const int n15  = lane & 15;
    const int q    = lane >> 4;

    const int bid = blockIdx.x;                   // 8b x 8ht x 8wt = 512 (all resident)
    const int b  = bid & 7;                       // XCD = batch
    const int ht = (bid >> 3) & 7;
    const int wt = bid >> 6;
    const int h0 = 8 * ht, w0 = 16 * wt;
    const int h  = h0 + wh;

    const float* f1b = f1 + (size_t)b * 256 * 8192;

    // ---- B stage setup: 32 x 1KB instrs/block/chunk; wave wh owns k = 4wh..4wh+3.
    // instr k: row r=k>>1 (gh=h0-4+r), c = (k&1)*16 + lane/4, group g = lane&3.
    // Source swizzle: data group gd = g ^ ((c>>1)&3)  (involution; read side matches).
    const uint32_t* bsrc[4];
    int bstep[4], bdst[4];
#pragma unroll
    for (int ki = 0; ki < 4; ++ki) {
        int k = 4 * wh + ki, r = k >> 1, gh = h0 - 4 + r;
        int c = (k & 1) * 16 + (lane >> 2);
        int gd = (lane & 3) ^ ((c >> 1) & 3);
        bool ok = (unsigned)gh < 64u;
        bsrc[ki]  = ok ? t2p + ((size_t)(b * 64 + gh) * 144 + (w0 + c)) * 128 + gd * 4
                       : wsZ + lane * 4;          // zero stripe (keeps vmcnt count uniform)
        bstep[ki] = ok ? 16 : 0;                  // +16 words (64B) per 32-ch chunk
        bdst[ki]  = k * 256;
    }

    // ---- A: lane (n15,q) loads ch 8q+j at (h, w0+n15); 8 dword loads per chunk
    const float* aP = f1b + (size_t)(8 * q) * 8192 + (size_t)h * 128 + w0 + n15;

    floatx4 acc[9][2];
#pragma unroll
    for (int di = 0; di < 9; ++di)
#pragma unroll
        for (int t = 0; t < 2; ++t)
            acc[di][t] = (floatx4){0.f, 0.f, 0.f, 0.f};

    // prologue: stage B(0) THEN issue A(0)  (order matters for vmcnt counting)
#pragma unroll
    for (int ki = 0; ki < 4; ++ki) { gld_lds16(bsrc[ki], &ldsB[bdst[ki]]); bsrc[ki] += bstep[ki]; }
    __builtin_amdgcn_sched_barrier(0);
    float rAn[8];
#pragma unroll
    for (int j = 0; j < 8; ++j) rAn[j] = aP[(size_t)j * 8192];

    const int rdB = n15 * 16 + ((q ^ ((n15 >> 1) & 3)) << 2);  // frag word offset (swizzled)

    for (int ch = 0; ch < 8; ++ch) {
        // in-flight: B(ch)[4, oldest] + A(ch)[8] -> vmcnt(8) drains B(ch) only (FIFO).
        asm volatile("s_waitcnt vmcnt(8)\n\ts_barrier" ::: "memory");
        const int cb = (ch & 1) * 8192;

        float rAc[8];
#pragma unroll
        for (int j = 0; j < 8; ++j) rAc[j] = rAn[j];   // consume A(ch) (compiler waits vmcnt)

        if (ch < 7) {
            const int nb = ((ch + 1) & 1) * 8192;
#pragma unroll
            for (int ki = 0; ki < 4; ++ki) { gld_lds16(bsrc[ki], &ldsB[nb + bdst[ki]]); bsrc[ki] += bstep[ki]; }
            __builtin_amdgcn_sched_barrier(0);         // pin B-stage before A-issue (FIFO order)
            aP += (size_t)32 * 8192;
#pragma unroll
            for (int j = 0; j < 8; ++j) rAn[j] = aP[(size_t)j * 8192];
        }

        // pack A(ch) -> bf16 frag (kp pairs ascending, lo = even channel)
        uint32_t aw0 = pack2(rAc[0], rAc[1]);
        uint32_t aw1 = pack2(rAc[2], rAc[3]);
        uint32_t aw2 = pack2(rAc[4], rAc[5]);
        uint32_t aw3 = pack2(rAc[6], rAc[7]);
        uintx4 av = {aw0, aw1, aw2, aw3};
        short8 a0 = __builtin_bit_cast(short8, av);

        const uint32_t* bufB = ldsB + cb;
#pragma unroll
        for (int di = 0; di < 9; ++di) {
            const uint32_t* p0 = bufB + (wh + di) * 512 + rdB;   // tile0: c = n15
            uintx4 v0 = *(const uintx4*)p0;                       // ds_read_b128
            uintx4 v1 = *(const uintx4*)(p0 + 128);               // tile1: c = 8 + n15
            short8 b0 = __builtin_bit_cast(short8, v0);
            short8 b1 = __builtin_bit_cast(short8, v1);
            acc[di][0] = __builtin_amdgcn_mfma_f32_16x16x32_bf16(a0, b0, acc[di][0], 0, 0, 0);
            acc[di][1] = __builtin_amdgcn_mfma_f32_16x16x32_bf16(a0, b1, acc[di][1], 0, 0, 0);
        }
    }

    // ---- epilogue: band extraction (verified). dj = t*8 + n15 - mp; t1 stores n15>=8.
    const size_t base = ((size_t)b * 81) * 8192 + (size_t)h * 128 + w0;
#pragma unroll
    for (int di = 0; di < 9; ++di) {
#pragma unroll
        for (int t = 0; t < 2; ++t) {
#pragma unroll
            for (int r = 0; r < 4; ++r) {
                int mp = 4 * q + r;
                int dj = t * 8 + n15 - mp;
                if (dj >= 0 && dj <= 8 && (t == 0 || n15 >= 8)) {
                    out[base + (size_t)(di * 9 + dj) * 8192 + mp] = acc[di][t][r];
                }
            }
        }
    }
}

// =====================================================================
// FALLBACK (verified R2 kernel) — used only if workspace is too small.
// =====================================================================
#define CS 18
#define A_WORDS (8 * 16 * CS)
#define B_ROWS  13
#define B_WORDS (B_ROWS * 24 * CS)

__device__ __forceinline__ short8 frag_ld(const uint32_t* p) {
    uintx2 lo = *(const uintx2*)p;
    uintx2 hi = *(const uintx2*)(p + 2);
    uintx4 v = {lo.x, lo.y, hi.x, hi.y};
    return __builtin_bit_cast(short8, v);
}

__global__ __launch_bounds__(512, 4)
void corr_kernel(const float* __restrict__ f1, const float* __restrict__ f2,
                 float* __restrict__ out) {
    __shared__ uint32_t ldsA[2 * A_WORDS];
    __shared__ uint32_t ldsB2[2 * B_WORDS];

    const int tid  = threadIdx.x;
    const int lane = tid & 63;
    const int wh   = tid >> 6;
    const int n15  = lane & 15;
    const int q    = lane >> 4;

    const int bid    = blockIdx.x;
    const int b      = bid & 7;
    const int dihalf = (bid >> 3) & 1;
    const int ht     = (bid >> 4) & 7;
    const int wt     = bid >> 7;

    const int w0 = wt * 16;
    const int h0 = ht * 8;
    const int h  = h0 + wh;

    const int diN    = dihalf ? 4 : 5;
    const int diBase = dihalf * 5;
    const int ghBase = dihalf ? (h0 + 1) : (h0 - 4);

    const float* f1b = f1 + (size_t)b * 256 * 8192;
    const float* f2b = f2 + (size_t)b * 256 * 8192;

    const int aw4 = tid & 3, akp = (tid >> 2) & 15, arow = tid >> 6;
    int aOffG = (2 * akp) * 8192 + (h0 + arow) * 128 + (w0 + 4 * aw4);
    const int aLds = (arow * 16 + 4 * aw4) * CS + akp;

    int bOffG[3]; int bLds[3]; uint32_t bMask[3];
#pragma unroll
    for (int s = 0; s < 3; ++s) {
        int t = tid + 512 * s;
        int w4 = t % 6;
        int r2 = t / 6;
        int kp = r2 & 15, row = r2 >> 4;
        int gh = ghBase + row;
        int gw = w0 - 4 + 4 * w4;
        bool live = (t < 1152);
        bool inb  = live && ((unsigned)gh < 64u) && ((unsigned)gw < 128u);
        bOffG[s] = inb ? ((2 * kp) * 8192 + gh * 128 + gw) : 0;
        bLds[s]  = live ? ((row * 24 + 4 * w4) * CS + kp) : ((12 * 24 + (tid & 7)) * CS);
        bMask[s] = inb ? 0xFFFFFFFFu : 0u;
    }

    floatx4 acc[5][2];
#pragma unroll
    for (int dl = 0; dl < 5; ++dl)
#pragma unroll
        for (int t = 0; t < 2; ++t)
            acc[dl][t] = (floatx4){0.f, 0.f, 0.f, 0.f};

    floatx4 rA[2], rB[3][2];
    uint32_t pkA[4], pkB[12];

    auto issue = [&]() {
        rA[0] = *(const floatx4*)(f1b + aOffG);
        rA[1] = *(const floatx4*)(f1b + aOffG + 8192);
        aOffG += 32 * 8192;
#pragma unroll
        for (int s = 0; s < 3; ++s) {
            rB[s][0] = *(const floatx4*)(f2b + bOffG[s]);
            rB[s][1] = *(const floatx4*)(f2b + bOffG[s] + 8192);
            bOffG[s] += 32 * 8192;
        }
    };
    auto packall = [&]() {
#pragma unroll
        for (int i = 0; i < 4; ++i) pkA[i] = pack2(rA[0][i], rA[1][i]);
#pragma unroll
        for (int s = 0; s < 3; ++s)
#pragma unroll
            for (int i = 0; i < 4; ++i)
                pkB[4 * s + i] = pack2(rB[s][0][i], rB[s][1][i]) & bMask[s];
    };

    issue(); packall();

    for (int ch = 0; ch < 8; ++ch) {
        uint32_t* bufA = ldsA + (ch & 1) * A_WORDS;
        uint32_t* bufB = ldsB2 + (ch & 1) * B_WORDS;
#pragma unroll
        for (int i = 0; i < 4; ++i) bufA[aLds + i * CS] = pkA[i];
#pragma unroll
        for (int s = 0; s < 3; ++s)
#pragma unroll
            for (int i = 0; i < 4; ++i) bufB[bLds[s] + i * CS] = pkB[4 * s + i];
        if (ch < 7) issue();
        __syncthreads();

        const uint32_t* pa = bufA + (wh * 16 + n15) * CS + 4 * q;
        short8 a0 = frag_ld(pa);
        const uint32_t* pb = bufB + (wh * 24 + n15) * CS + 4 * q;
#pragma unroll
        for (int dl = 0; dl < 5; ++dl) {
            if (dl < diN) {
                const uint32_t* p = pb + dl * (24 * CS);
                short8 b0 = frag_ld(p);
                short8 b1 = frag_ld(p + 8 * CS);
                acc[dl][0] = __builtin_amdgcn_mfma_f32_16x16x32_bf16(a0, b0, acc[dl][0], 0, 0, 0);
                acc[dl][1] = __builtin_amdgcn_mfma_f32_16x16x32_bf16(a0, b1, acc[dl][1], 0, 0, 0);
            }
        }
        if (ch < 7) packall();
    }

    const size_t base = ((size_t)b * 81) * 8192 + (size_t)h * 128 + w0;
#pragma unroll
    for (int dl = 0; dl < 5; ++dl) {
        if (dl < diN) {
            const int dio = diBase + dl;
#pragma unroll
            for (int t = 0; t < 2; ++t) {
#pragma unroll
                for (int r = 0; r < 4; ++r) {
                    int mp = 4 * q + r;
                    int dj = t * 8 + n15 - mp;
                    if (dj >= 0 && dj <= 8 && (t == 0 || n15 >= 8)) {
                        out[base + (size_t)(dio * 9 + dj) * 8192 + mp] = acc[dl][t][r];
                    }
                }
            }
        }
    }
}

extern "C" void kernel_launch(void* const* d_in, const int* in_sizes, int n_in,
                              void* d_out, int out_size, void* d_ws, size_t ws_size,
                              hipStream_t stream) {
    const float* f1 = (const float*)d_in[0];
    const float* f2 = (const float*)d_in[1];
    float* out = (float*)d_out;
    if (ws_size >= WS_NEED && d_ws != nullptr) {
        uint32_t* t2p = (uint32_t*)d_ws;
        transpose_f2<<<dim3(2048), dim3(256), 0, stream>>>(f2, t2p);
        corr2<<<dim3(512), dim3(512), 0, stream>>>(f1, t2p, t2p + T2P_WORDS, out);
    } else {
        corr_kernel<<<dim3(1024), dim3(512), 0, stream>>>(f1, f2, out);
    }
}

// Round 4
// 184.200 us; speedup vs baseline: 1.0244x; 1.0234x over previous
//
#include <hip/hip_runtime.h>
#include <cstdint>

typedef __attribute__((ext_vector_type(8))) short short8;     // 8 bf16 (4 VGPRs)
typedef __attribute__((ext_vector_type(4))) float floatx4;
typedef __attribute__((ext_vector_type(2))) unsigned int uintx2;
typedef __attribute__((ext_vector_type(4))) unsigned int uintx4;

__device__ __forceinline__ uint32_t pack2(float a, float b) {
    uint32_t ua = __builtin_bit_cast(uint32_t, a);
    uint32_t ub = __builtin_bit_cast(uint32_t, b);
    ua = (ua + 0x7FFFu + ((ua >> 16) & 1u)) >> 16;   // RNE (verified, absmax 0.5)
    ub = (ub + 0x7FFFu + ((ub >> 16) & 1u)) >> 16;
    return ua | (ub << 16);                           // lo = even channel, hi = odd channel
}

// =====================================================================
// PASS 1 (unchanged, verified): f2 [8,256,64,128] f32 -> t2p bf16 kpair
// [8][64][144][128] u32, W padded +-4, plus 4KB zero stripe.
// =====================================================================
#define T2P_WORDS ((size_t)8 * 64 * 144 * 128)   // 36 MiB
#define WS_NEED   (T2P_WORDS * 4 + 4096)

__global__ __launch_bounds__(256)
void transpose_f2(const float* __restrict__ f2, uint32_t* __restrict__ t2p) {
    __shared__ float t[64][33];
    const int tid = threadIdx.x;
    const int bid = blockIdx.x;                   // 8b x 64h x 4wt = 2048
    const int b = bid & 7, h = (bid >> 3) & 63, wt = bid >> 9;
    const int w0 = wt * 32;
    const float* f2b = f2 + (size_t)b * 256 * 8192 + (size_t)h * 128 + w0;
    uint32_t* t2row = t2p + ((size_t)(b * 64 + h) * 144 + (w0 + 4)) * 128;

    const int rw = tid & 31, rc8 = tid >> 5;
    const int kpL = tid & 31, wg = tid >> 5;

    for (int cc = 0; cc < 4; ++cc) {
        if (cc) __syncthreads();
#pragma unroll
        for (int i = 0; i < 8; ++i)
            t[rc8 * 8 + i][rw] = f2b[(size_t)(cc * 64 + rc8 * 8 + i) * 8192 + rw];
        __syncthreads();
#pragma unroll
        for (int j = 0; j < 4; ++j) {
            int w = wg * 4 + j;
            t2row[(size_t)w * 128 + cc * 32 + kpL] = pack2(t[2 * kpL][w], t[2 * kpL + 1][w]);
        }
    }
    if (wt == 0) {
        uint32_t* p = t2p + ((size_t)(b * 64 + h) * 144) * 128;
        for (int idx = tid; idx < 512; idx += 256) p[idx] = 0;
    }
    if (wt == 3) {
        uint32_t* p = t2p + ((size_t)(b * 64 + h) * 144 + 132) * 128;
        for (int idx = tid; idx < 1536; idx += 256) p[idx] = 0;
    }
    if (bid == 0) {
        uint32_t* z = t2p + T2P_WORDS;
        for (int idx = tid; idx < 1024; idx += 256) z[idx] = 0;
    }
}

// =====================================================================
// PASS 2 v2: explicit 2-deep A register pipeline + counted-vmcnt barriers
// (never a mid-loop full drain) + per-block channel-phase rotation.
// B path identical to R3 (verified: 0 bank conflicts): gld_lds 16B with
// source-side swizzle, double-buffered 2x32KB LDS.
// =====================================================================
#define AS1 __attribute__((address_space(1)))
#define AS3 __attribute__((address_space(3)))

__device__ __forceinline__ void gld_lds16(const uint32_t* src, uint32_t* dst) {
    __builtin_amdgcn_global_load_lds((const AS1 void*)src, (AS3 void*)dst, 16, 0, 0);
}

__global__ __launch_bounds__(512, 3)   // reg cap 170: stop allocator from serializing the A pipe
void corr2(const float* __restrict__ f1, const uint32_t* __restrict__ t2p,
           const uint32_t* __restrict__ wsZ, float* __restrict__ out) {
    __shared__ uint32_t ldsB[2 * 8192];           // 2 x [16 rows][32 c][16 words] = 64 KB

    const int tid  = threadIdx.x;
    const int lane = tid & 63;
    const int wh   = tid >> 6;
    const int n15  = lane & 15;
    const int q    = lane >> 4;

    const int bid = blockIdx.x;                   // 8b x 8ht x 8wt = 512
    const int b  = bid & 7;                       // XCD = batch
    const int ht = (bid >> 3) & 7;
    const int wt = bid >> 6;
    const int h0 = 8 * ht, w0 = 16 * wt;
    const int h  = h0 + wh;
    const int p  = (ht + wt) & 7;                 // channel-phase rotation (sum is commutative)

    const float* f1b = f1 + (size_t)b * 256 * 8192;

    // ---- B stage setup (cc=0 bases; +cc*16 words per chunk)
    const uint32_t* bbase[4];
    int bstep[4], bdst[4];
#pragma unroll
    for (int ki = 0; ki < 4; ++ki) {
        int k = 4 * wh + ki, r = k >> 1, gh = h0 - 4 + r;
        int c = (k & 1) * 16 + (lane >> 2);
        int gd = (lane & 3) ^ ((c >> 1) & 3);
        bool ok = (unsigned)gh < 64u;
        bbase[ki] = ok ? t2p + ((size_t)(b * 64 + gh) * 144 + (w0 + c)) * 128 + gd * 4
                       : wsZ + lane * 4;          // zero stripe
        bstep[ki] = ok ? 16 : 0;
        bdst[ki]  = k * 256;
    }

    // ---- A base: lane (n15,q) covers (h, w0+n15), channels 32cc+8q+j
    const float* aBase = f1b + (size_t)h * 128 + w0 + n15;

    floatx4 acc[9][2];
#pragma unroll
    for (int di = 0; di < 9; ++di)
#pragma unroll
        for (int t = 0; t < 2; ++t)
            acc[di][t] = (floatx4){0.f, 0.f, 0.f, 0.f};

    const int rdB = n15 * 16 + ((q ^ ((n15 >> 1) & 3)) << 2);

    auto stageB = [&](int bufsel, int cc) {
        uint32_t* dst = ldsB + bufsel * 8192;
#pragma unroll
        for (int ki = 0; ki < 4; ++ki)
            gld_lds16(bbase[ki] + (size_t)cc * bstep[ki], &dst[bdst[ki]]);
    };
    auto loadA = [&](float* r, int cc) {
        const float* ap = aBase + (size_t)(32 * cc + 8 * q) * 8192;
#pragma unroll
        for (int j = 0; j < 8; ++j) r[j] = ap[(size_t)j * 8192];
    };
    auto packA = [&](const float* r) -> short8 {
        uintx4 av = {pack2(r[0], r[1]), pack2(r[2], r[3]),
                     pack2(r[4], r[5]), pack2(r[6], r[7])};
        return __builtin_bit_cast(short8, av);
    };
    auto mfma9 = [&](int bufsel, short8 a0) {
        const uint32_t* bufB = ldsB + bufsel * 8192;
#pragma unroll
        for (int di = 0; di < 9; ++di) {
            const uint32_t* p0 = bufB + (wh + di) * 512 + rdB;
            uintx4 v0 = *(const uintx4*)p0;                    // ds_read_b128, conflict-free
            uintx4 v1 = *(const uintx4*)(p0 + 128);
            short8 b0 = __builtin_bit_cast(short8, v0);
            short8 b1 = __builtin_bit_cast(short8, v1);
            acc[di][0] = __builtin_amdgcn_mfma_f32_16x16x32_bf16(a0, b0, acc[di][0], 0, 0, 0);
            acc[di][1] = __builtin_amdgcn_mfma_f32_16x16x32_bf16(a0, b1, acc[di][1], 0, 0, 0);
        }
    };

    float rA0[8], rA1[8];

    // ---- prologue: B(0) B(1) into both buffers, A(0) A(1) into both reg sets.
    // Issue order (FIFO for vmcnt): B0(4) A0(8) B1(4) A1(8) = 24 outstanding.
    stageB(0, p);
    __builtin_amdgcn_sched_barrier(0);
    loadA(rA0, p);
    __builtin_amdgcn_sched_barrier(0);
    stageB(1, (p + 1) & 7);
    __builtin_amdgcn_sched_barrier(0);
    loadA(rA1, (p + 1) & 7);
    __builtin_amdgcn_sched_barrier(0);

    // Chunk K: barrier waits B(K) [and A(K), older] via counted vmcnt; stage B(K+1)
    // into the buffer chunk K-1 just finished; pack A(K); reload the SAME reg set
    // for A(K+2) (2-deep); compute. vmcnt: K=0 -> 20 (A0 B1 A1 younger than B0),
    // K=1 -> 16 (A1 A2), steady -> 8 (A(K+1)), K=7 -> 0 (nothing younger than B7).
#define CHUNK(K, VM, RS)                                                      \
    {                                                                         \
        asm volatile("s_waitcnt vmcnt(" #VM ")\n\ts_barrier" ::: "memory");   \
        if ((K) >= 1 && (K) < 7) stageB(((K) + 1) & 1, ((K) + 1 + p) & 7);    \
        __builtin_amdgcn_sched_barrier(0);                                    \
        short8 a0 = packA(RS);                                                \
        if ((K) < 6) loadA(RS, ((K) + 2 + p) & 7);                            \
        __builtin_amdgcn_sched_barrier(0);                                    \
        mfma9((K) & 1, a0);                                                   \
    }

    CHUNK(0, 20, rA0)
    CHUNK(1, 16, rA1)
    CHUNK(2, 8,  rA0)
    CHUNK(3, 8,  rA1)
    CHUNK(4, 8,  rA0)
    CHUNK(5, 8,  rA1)
    CHUNK(6, 8,  rA0)
    CHUNK(7, 0,  rA1)
#undef CHUNK

    // ---- epilogue: band extraction (verified). dj = t*8 + n15 - mp; t1 stores n15>=8.
    const size_t base = ((size_t)b * 81) * 8192 + (size_t)h * 128 + w0;
#pragma unroll
    for (int di = 0; di < 9; ++di) {
#pragma unroll
        for (int t = 0; t < 2; ++t) {
#pragma unroll
            for (int r = 0; r < 4; ++r) {
                int mp = 4 * q + r;
                int dj = t * 8 + n15 - mp;
                if (dj >= 0 && dj <= 8 && (t == 0 || n15 >= 8)) {
                    out[base + (size_t)(di * 9 + dj) * 8192 + mp] = acc[di][t][r];
                }
            }
        }
    }
}

// =====================================================================
// FALLBACK (verified R2 kernel) — used only if workspace is too small.
// =====================================================================
#define CS 18
#define A_WORDS (8 * 16 * CS)
#define B_ROWS  13
#define B_WORDS (B_ROWS * 24 * CS)

__device__ __forceinline__ short8 frag_ld(const uint32_t* p) {
    uintx2 lo = *(const uintx2*)p;
    uintx2 hi = *(const uintx2*)(p + 2);
    uintx4 v = {lo.x, lo.y, hi.x, hi.y};
    return __builtin_bit_cast(short8, v);
}

__global__ __launch_bounds__(512, 4)
void corr_kernel(const float* __restrict__ f1, const float* __restrict__ f2,
                 float* __restrict__ out) {
    __shared__ uint32_t ldsA[2 * A_WORDS];
    __shared__ uint32_t ldsB2[2 * B_WORDS];

    const int tid  = threadIdx.x;
    const int lane = tid & 63;
    const int wh   = tid >> 6;
    const int n15  = lane & 15;
    const int q    = lane >> 4;

    const int bid    = blockIdx.x;
    const int b      = bid & 7;
    const int dihalf = (bid >> 3) & 1;
    const int ht     = (bid >> 4) & 7;
    const int wt     = bid >> 7;

    const int w0 = wt * 16;
    const int h0 = ht * 8;
    const int h  = h0 + wh;

    const int diN    = dihalf ? 4 : 5;
    const int diBase = dihalf * 5;
    const int ghBase = dihalf ? (h0 + 1) : (h0 - 4);

    const float* f1b = f1 + (size_t)b * 256 * 8192;
    const float* f2b = f2 + (size_t)b * 256 * 8192;

    const int aw4 = tid & 3, akp = (tid >> 2) & 15, arow = tid >> 6;
    int aOffG = (2 * akp) * 8192 + (h0 + arow) * 128 + (w0 + 4 * aw4);
    const int aLds = (arow * 16 + 4 * aw4) * CS + akp;

    int bOffG[3]; int bLds[3]; uint32_t bMask[3];
#pragma unroll
    for (int s = 0; s < 3; ++s) {
        int t = tid + 512 * s;
        int w4 = t % 6;
        int r2 = t / 6;
        int kp = r2 & 15, row = r2 >> 4;
        int gh = ghBase + row;
        int gw = w0 - 4 + 4 * w4;
        bool live = (t < 1152);
        bool inb  = live && ((unsigned)gh < 64u) && ((unsigned)gw < 128u);
        bOffG[s] = inb ? ((2 * kp) * 8192 + gh * 128 + gw) : 0;
        bLds[s]  = live ? ((row * 24 + 4 * w4) * CS + kp) : ((12 * 24 + (tid & 7)) * CS);
        bMask[s] = inb ? 0xFFFFFFFFu : 0u;
    }

    floatx4 acc[5][2];
#pragma unroll
    for (int dl = 0; dl < 5; ++dl)
#pragma unroll
        for (int t = 0; t < 2; ++t)
            acc[dl][t] = (floatx4){0.f, 0.f, 0.f, 0.f};

    floatx4 rA[2], rB[3][2];
    uint32_t pkA[4], pkB[12];

    auto issue = [&]() {
        rA[0] = *(const floatx4*)(f1b + aOffG);
        rA[1] = *(const floatx4*)(f1b + aOffG + 8192);
        aOffG += 32 * 8192;
#pragma unroll
        for (int s = 0; s < 3; ++s) {
            rB[s][0] = *(const floatx4*)(f2b + bOffG[s]);
            rB[s][1] = *(const floatx4*)(f2b + bOffG[s] + 8192);
            bOffG[s] += 32 * 8192;
        }
    };
    auto packall = [&]() {
#pragma unroll
        for (int i = 0; i < 4; ++i) pkA[i] = pack2(rA[0][i], rA[1][i]);
#pragma unroll
        for (int s = 0; s < 3; ++s)
#pragma unroll
            for (int i = 0; i < 4; ++i)
                pkB[4 * s + i] = pack2(rB[s][0][i], rB[s][1][i]) & bMask[s];
    };

    issue(); packall();

    for (int ch = 0; ch < 8; ++ch) {
        uint32_t* bufA = ldsA + (ch & 1) * A_WORDS;
        uint32_t* bufB = ldsB2 + (ch & 1) * B_WORDS;
#pragma unroll
        for (int i = 0; i < 4; ++i) bufA[aLds + i * CS] = pkA[i];
#pragma unroll
        for (int s = 0; s < 3; ++s)
#pragma unroll
            for (int i = 0; i < 4; ++i) bufB[bLds[s] + i * CS] = pkB[4 * s + i];
        if (ch < 7) issue();
        __syncthreads();

        const uint32_t* pa = bufA + (wh * 16 + n15) * CS + 4 * q;
        short8 a0 = frag_ld(pa);
        const uint32_t* pb = bufB + (wh * 24 + n15) * CS + 4 * q;
#pragma unroll
        for (int dl = 0; dl < 5; ++dl) {
            if (dl < diN) {
                const uint32_t* pp = pb + dl * (24 * CS);
                short8 b0 = frag_ld(pp);
                short8 b1 = frag_ld(pp + 8 * CS);
                acc[dl][0] = __builtin_amdgcn_mfma_f32_16x16x32_bf16(a0, b0, acc[dl][0], 0, 0, 0);
                acc[dl][1] = __builtin_amdgcn_mfma_f32_16x16x32_bf16(a0, b1, acc[dl][1], 0, 0, 0);
            }
        }
        if (ch < 7) packall();
    }

    const size_t base = ((size_t)b * 81) * 8192 + (size_t)h * 128 + w0;
#pragma unroll
    for (int dl = 0; dl < 5; ++dl) {
        if (dl < diN) {
            const int dio = diBase + dl;
#pragma unroll
            for (int t = 0; t < 2; ++t) {
#pragma unroll
                for (int r = 0; r < 4; ++r) {
                    int mp = 4 * q + r;
                    int dj = t * 8 + n15 - mp;
                    if (dj >= 0 && dj <= 8 && (t == 0 || n15 >= 8)) {
                        out[base + (size_t)(dio * 9 + dj) * 8192 + mp] = acc[dl][t][r];
                    }
                }
            }
        }
    }
}

extern "C" void kernel_launch(void* const* d_in, const int* in_sizes, int n_in,
                              void* d_out, int out_size, void* d_ws, size_t ws_size,
                              hipStream_t stream) {
    const float* f1 = (const float*)d_in[0];
    const float* f2 = (const float*)d_in[1];
    float* out = (float*)d_out;
    if (ws_size >= WS_NEED && d_ws != nullptr) {
        uint32_t* t2p = (uint32_t*)d_ws;
        transpose_f2<<<dim3(2048), dim3(256), 0, stream>>>(f2, t2p);
        corr2<<<dim3(512), dim3(512), 0, stream>>>(f1, t2p, t2p + T2P_WORDS, out);
    } else {
        corr_kernel<<<dim3(1024), dim3(512), 0, stream>>>(f1, f2, out);
    }
}

// Round 5
// 177.344 us; speedup vs baseline: 1.0640x; 1.0387x over previous
//
#include <hip/hip_runtime.h>
#include <cstdint>

typedef __attribute__((ext_vector_type(8))) short short8;     // 8 bf16 (4 VGPRs)
typedef __attribute__((ext_vector_type(4))) float floatx4;
typedef __attribute__((ext_vector_type(2))) unsigned int uintx2;
typedef __attribute__((ext_vector_type(4))) unsigned int uintx4;

__device__ __forceinline__ uint32_t pack2(float a, float b) {
    uint32_t ua = __builtin_bit_cast(uint32_t, a);
    uint32_t ub = __builtin_bit_cast(uint32_t, b);
    ua = (ua + 0x7FFFu + ((ua >> 16) & 1u)) >> 16;   // RNE (verified, absmax 0.5)
    ub = (ub + 0x7FFFu + ((ub >> 16) & 1u)) >> 16;
    return ua | (ub << 16);                           // lo = even channel, hi = odd channel
}

// =====================================================================
// PASS 1: f2 [8,256,64,128] f32 -> t2p bf16-kpair, CHANNEL-CHUNK-OUTER:
//   t2p[cc2 0..7][b][h][wp 0..143][word 0..15],  word = kp & 15, cc2 = kp >> 4
// so pass 2's per-chunk reads are CONTIGUOUS (full 128B-line utilization)
// and the per-phase working set is one 4.5 MB slab (L2-resident per XCD).
// W padded +-4 (wp = w+4, pads zero) + 4KB zero stripe at the end.
// =====================================================================
#define CC_SLAB  ((size_t)8 * 64 * 2304)          // words per cc2 slab (8b x 64h x 144*16)
#define T2P_WORDS (8 * CC_SLAB)                   // 9,437,184 words = 36 MiB
#define WS_NEED   (T2P_WORDS * 4 + 4096)

__global__ __launch_bounds__(256)
void transpose_f2(const float* __restrict__ f2, uint32_t* __restrict__ t2p) {
    __shared__ float t[64][33];
    const int tid = threadIdx.x;
    const int bid = blockIdx.x;                   // 8b x 64h x 4wt = 2048
    const int b = bid & 7, h = (bid >> 3) & 63, wt = bid >> 9;
    const int w0 = wt * 32;
    const float* f2b = f2 + (size_t)b * 256 * 8192 + (size_t)h * 128 + w0;

    const int rw = tid & 31, rc8 = tid >> 5;      // read: w lane, ch-group (8 ch each)
    const int tp = tid & 127, rr = tid >> 7;      // write: region rr in {0,1}, tp 0..127
    const int m  = tp & 15;                        // word-in-cell (= kp & 15)

    for (int cc = 0; cc < 4; ++cc) {              // 64 channels per iter -> cc2 = 2cc+rr
        if (cc) __syncthreads();
#pragma unroll
        for (int i = 0; i < 8; ++i)
            t[rc8 * 8 + i][rw] = f2b[(size_t)(cc * 64 + rc8 * 8 + i) * 8192 + rw];
        __syncthreads();
        const int cc2 = 2 * cc + rr;
        uint32_t* dst = t2p + (size_t)cc2 * CC_SLAB
                        + ((size_t)b * 64 + h) * 2304 + (size_t)(w0 + 4) * 16;
#pragma unroll
        for (int i = 0; i < 4; ++i) {
            int d = i * 128 + tp;                  // 0..511; 512B contiguous per instr
            int j = d >> 4;                        // w offset 0..31 (d&15 == m)
            dst[d] = pack2(t[rr * 32 + 2 * m][j], t[rr * 32 + 2 * m + 1][j]);
        }
    }
    // zero pads: wp 0..3 (wt==0) and wp 132..143 (wt==3), for all 8 cc2 slabs
    if (wt == 0) {
        for (int idx = tid; idx < 512; idx += 256) {
            int cc2 = idx >> 6, o = idx & 63;      // 4 wp x 16 words
            t2p[(size_t)cc2 * CC_SLAB + ((size_t)b * 64 + h) * 2304 + o] = 0;
        }
    }
    if (wt == 3) {
        for (int idx = tid; idx < 1536; idx += 256) {
            int cc2 = idx / 192, o = idx % 192;    // 12 wp x 16 words
            t2p[(size_t)cc2 * CC_SLAB + ((size_t)b * 64 + h) * 2304 + 132 * 16 + o] = 0;
        }
    }
    if (bid == 0) {
        uint32_t* z = t2p + T2P_WORDS;
        for (int idx = tid; idx < 1024; idx += 256) z[idx] = 0;
    }
}

// =====================================================================
// PASS 2 v3: R4's 2-deep A pipeline + counted vmcnt, with the new
// cc-outer B layout (contiguous per-chunk reads, L2-resident slab) and
// NO channel-phase rotation (phase-coherent blocks -> L2 temporal hits).
// =====================================================================
#define AS1 __attribute__((address_space(1)))
#define AS3 __attribute__((address_space(3)))

__device__ __forceinline__ void gld_lds16(const uint32_t* src, uint32_t* dst) {
    __builtin_amdgcn_global_load_lds((const AS1 void*)src, (AS3 void*)dst, 16, 0, 0);
}

__global__ __launch_bounds__(512, 3)
void corr2(const float* __restrict__ f1, const uint32_t* __restrict__ t2p,
           const uint32_t* __restrict__ wsZ, float* __restrict__ out) {
    __shared__ uint32_t ldsB[2 * 8192];           // 2 x [16 rows][32 c][16 words] = 64 KB

    const int tid  = threadIdx.x;
    const int lane = tid & 63;
    const int wh   = tid >> 6;
    const int n15  = lane & 15;
    const int q    = lane >> 4;

    const int bid = blockIdx.x;                   // 8b x 8ht x 8wt = 512
    const int b  = bid & 7;                       // XCD = batch
    const int ht = (bid >> 3) & 7;
    const int wt = bid >> 6;
    const int h0 = 8 * ht, w0 = 16 * wt;
    const int h  = h0 + wh;

    const float* f1b = f1 + (size_t)b * 256 * 8192;

    // ---- B stage setup (cc=0 bases; +CC_SLAB per chunk). Per instruction:
    // 16 c-cells x 64B = 1KB CONTIGUOUS (cc-outer layout), gd sub-block swizzle
    // preserved so LDS content (and the verified read side) is unchanged.
    const uint32_t* bbase[4];
    size_t bstep[4];
    int bdst[4];
#pragma unroll
    for (int ki = 0; ki < 4; ++ki) {
        int k = 4 * wh + ki, r = k >> 1, gh = h0 - 4 + r;
        int c = (k & 1) * 16 + (lane >> 2);
        int gd = (lane & 3) ^ ((c >> 1) & 3);
        bool ok = (unsigned)gh < 64u;
        bbase[ki] = ok ? t2p + ((size_t)b * 64 + gh) * 2304 + (size_t)(w0 + c) * 16 + gd * 4
                       : wsZ + lane * 4;          // zero stripe
        bstep[ki] = ok ? CC_SLAB : 0;
        bdst[ki]  = k * 256;
    }

    // ---- A base: lane (n15,q) covers (h, w0+n15), channels 32cc+8q+j
    const float* aBase = f1b + (size_t)h * 128 + w0 + n15;

    floatx4 acc[9][2];
#pragma unroll
    for (int di = 0; di < 9; ++di)
#pragma unroll
        for (int t = 0; t < 2; ++t)
            acc[di][t] = (floatx4){0.f, 0.f, 0.f, 0.f};

    const int rdB = n15 * 16 + ((q ^ ((n15 >> 1) & 3)) << 2);

    auto stageB = [&](int bufsel, int cc) {
        uint32_t* dst = ldsB + bufsel * 8192;
#pragma unroll
        for (int ki = 0; ki < 4; ++ki)
            gld_lds16(bbase[ki] + (size_t)cc * bstep[ki], &dst[bdst[ki]]);
    };
    auto loadA = [&](float* r, int cc) {
        const float* ap = aBase + (size_t)(32 * cc + 8 * q) * 8192;
#pragma unroll
        for (int j = 0; j < 8; ++j) r[j] = ap[(size_t)j * 8192];
    };
    auto packA = [&](const float* r) -> short8 {
        uintx4 av = {pack2(r[0], r[1]), pack2(r[2], r[3]),
                     pack2(r[4], r[5]), pack2(r[6], r[7])};
        return __builtin_bit_cast(short8, av);
    };
    auto mfma9 = [&](int bufsel, short8 a0) {
        const uint32_t* bufB = ldsB + bufsel * 8192;
#pragma unroll
        for (int di = 0; di < 9; ++di) {
            const uint32_t* p0 = bufB + (wh + di) * 512 + rdB;
            uintx4 v0 = *(const uintx4*)p0;                    // ds_read_b128, conflict-free
            uintx4 v1 = *(const uintx4*)(p0 + 128);
            short8 b0 = __builtin_bit_cast(short8, v0);
            short8 b1 = __builtin_bit_cast(short8, v1);
            acc[di][0] = __builtin_amdgcn_mfma_f32_16x16x32_bf16(a0, b0, acc[di][0], 0, 0, 0);
            acc[di][1] = __builtin_amdgcn_mfma_f32_16x16x32_bf16(a0, b1, acc[di][1], 0, 0, 0);
        }
    };

    float rA0[8], rA1[8];

    // prologue (FIFO order for vmcnt): B0(4) A0(8) B1(4) A1(8) = 24 outstanding
    stageB(0, 0);
    __builtin_amdgcn_sched_barrier(0);
    loadA(rA0, 0);
    __builtin_amdgcn_sched_barrier(0);
    stageB(1, 1);
    __builtin_amdgcn_sched_barrier(0);
    loadA(rA1, 1);
    __builtin_amdgcn_sched_barrier(0);

    // Chunk K: counted vmcnt drains exactly B(K); stage B(K+1); pack A(K);
    // reload same reg set for A(K+2); compute. Never a mid-loop full drain.
#define CHUNK(K, VM, RS)                                                      \
    {                                                                         \
        asm volatile("s_waitcnt vmcnt(" #VM ")\n\ts_barrier" ::: "memory");   \
        if ((K) >= 1 && (K) < 7) stageB(((K) + 1) & 1, (K) + 1);              \
        __builtin_amdgcn_sched_barrier(0);                                    \
        short8 a0 = packA(RS);                                                \
        if ((K) < 6) loadA(RS, (K) + 2);                                      \
        __builtin_amdgcn_sched_barrier(0);                                    \
        mfma9((K) & 1, a0);                                                   \
    }

    CHUNK(0, 20, rA0)
    CHUNK(1, 16, rA1)
    CHUNK(2, 8,  rA0)
    CHUNK(3, 8,  rA1)
    CHUNK(4, 8,  rA0)
    CHUNK(5, 8,  rA1)
    CHUNK(6, 8,  rA0)
    CHUNK(7, 0,  rA1)
#undef CHUNK

    // ---- epilogue: band extraction (verified). dj = t*8 + n15 - mp; t1 stores n15>=8.
    const size_t base = ((size_t)b * 81) * 8192 + (size_t)h * 128 + w0;
#pragma unroll
    for (int di = 0; di < 9; ++di) {
#pragma unroll
        for (int t = 0; t < 2; ++t) {
#pragma unroll
            for (int r = 0; r < 4; ++r) {
                int mp = 4 * q + r;
                int dj = t * 8 + n15 - mp;
                if (dj >= 0 && dj <= 8 && (t == 0 || n15 >= 8)) {
                    out[base + (size_t)(di * 9 + dj) * 8192 + mp] = acc[di][t][r];
                }
            }
        }
    }
}

// =====================================================================
// FALLBACK (verified R2 kernel) — used only if workspace is too small.
// =====================================================================
#define CS 18
#define A_WORDS (8 * 16 * CS)
#define B_ROWS  13
#define B_WORDS (B_ROWS * 24 * CS)

__device__ __forceinline__ short8 frag_ld(const uint32_t* p) {
    uintx2 lo = *(const uintx2*)p;
    uintx2 hi = *(const uintx2*)(p + 2);
    uintx4 v = {lo.x, lo.y, hi.x, hi.y};
    return __builtin_bit_cast(short8, v);
}

__global__ __launch_bounds__(512, 4)
void corr_kernel(const float* __restrict__ f1, const float* __restrict__ f2,
                 float* __restrict__ out) {
    __shared__ uint32_t ldsA[2 * A_WORDS];
    __shared__ uint32_t ldsB2[2 * B_WORDS];

    const int tid  = threadIdx.x;
    const int lane = tid & 63;
    const int wh   = tid >> 6;
    const int n15  = lane & 15;
    const int q    = lane >> 4;

    const int bid    = blockIdx.x;
    const int b      = bid & 7;
    const int dihalf = (bid >> 3) & 1;
    const int ht     = (bid >> 4) & 7;
    const int wt     = bid >> 7;

    const int w0 = wt * 16;
    const int h0 = ht * 8;
    const int h  = h0 + wh;

    const int diN    = dihalf ? 4 : 5;
    const int diBase = dihalf * 5;
    const int ghBase = dihalf ? (h0 + 1) : (h0 - 4);

    const float* f1b = f1 + (size_t)b * 256 * 8192;
    const float* f2b = f2 + (size_t)b * 256 * 8192;

    const int aw4 = tid & 3, akp = (tid >> 2) & 15, arow = tid >> 6;
    int aOffG = (2 * akp) * 8192 + (h0 + arow) * 128 + (w0 + 4 * aw4);
    const int aLds = (arow * 16 + 4 * aw4) * CS + akp;

    int bOffG[3]; int bLds[3]; uint32_t bMask[3];
#pragma unroll
    for (int s = 0; s < 3; ++s) {
        int t = tid + 512 * s;
        int w4 = t % 6;
        int r2 = t / 6;
        int kp = r2 & 15, row = r2 >> 4;
        int gh = ghBase + row;
        int gw = w0 - 4 + 4 * w4;
        bool live = (t < 1152);
        bool inb  = live && ((unsigned)gh < 64u) && ((unsigned)gw < 128u);
        bOffG[s] = inb ? ((2 * kp) * 8192 + gh * 128 + gw) : 0;
        bLds[s]  = live ? ((row * 24 + 4 * w4) * CS + kp) : ((12 * 24 + (tid & 7)) * CS);
        bMask[s] = inb ? 0xFFFFFFFFu : 0u;
    }

    floatx4 acc[5][2];
#pragma unroll
    for (int dl = 0; dl < 5; ++dl)
#pragma unroll
        for (int t = 0; t < 2; ++t)
            acc[dl][t] = (floatx4){0.f, 0.f, 0.f, 0.f};

    floatx4 rA[2], rB[3][2];
    uint32_t pkA[4], pkB[12];

    auto issue = [&]() {
        rA[0] = *(const floatx4*)(f1b + aOffG);
        rA[1] = *(const floatx4*)(f1b + aOffG + 8192);
        aOffG += 32 * 8192;
#pragma unroll
        for (int s = 0; s < 3; ++s) {
            rB[s][0] = *(const floatx4*)(f2b + bOffG[s]);
            rB[s][1] = *(const floatx4*)(f2b + bOffG[s] + 8192);
            bOffG[s] += 32 * 8192;
        }
    };
    auto packall = [&]() {
#pragma unroll
        for (int i = 0; i < 4; ++i) pkA[i] = pack2(rA[0][i], rA[1][i]);
#pragma unroll
        for (int s = 0; s < 3; ++s)
#pragma unroll
            for (int i = 0; i < 4; ++i)
                pkB[4 * s + i] = pack2(rB[s][0][i], rB[s][1][i]) & bMask[s];
    };

    issue(); packall();

    for (int ch = 0; ch < 8; ++ch) {
        uint32_t* bufA = ldsA + (ch & 1) * A_WORDS;
        uint32_t* bufB = ldsB2 + (ch & 1) * B_WORDS;
#pragma unroll
        for (int i = 0; i < 4; ++i) bufA[aLds + i * CS] = pkA[i];
#pragma unroll
        for (int s = 0; s < 3; ++s)
#pragma unroll
            for (int i = 0; i < 4; ++i) bufB[bLds[s] + i * CS] = pkB[4 * s + i];
        if (ch < 7) issue();
        __syncthreads();

        const uint32_t* pa = bufA + (wh * 16 + n15) * CS + 4 * q;
        short8 a0 = frag_ld(pa);
        const uint32_t* pb = bufB + (wh * 24 + n15) * CS + 4 * q;
#pragma unroll
        for (int dl = 0; dl < 5; ++dl) {
            if (dl < diN) {
                const uint32_t* pp = pb + dl * (24 * CS);
                short8 b0 = frag_ld(pp);
                short8 b1 = frag_ld(pp + 8 * CS);
                acc[dl][0] = __builtin_amdgcn_mfma_f32_16x16x32_bf16(a0, b0, acc[dl][0], 0, 0, 0);
                acc[dl][1] = __builtin_amdgcn_mfma_f32_16x16x32_bf16(a0, b1, acc[dl][1], 0, 0, 0);
            }
        }
        if (ch < 7) packall();
    }

    const size_t base = ((size_t)b * 81) * 8192 + (size_t)h * 128 + w0;
#pragma unroll
    for (int dl = 0; dl < 5; ++dl) {
        if (dl < diN) {
            const int dio = diBase + dl;
#pragma unroll
            for (int t = 0; t < 2; ++t) {
#pragma unroll
                for (int r = 0; r < 4; ++r) {
                    int mp = 4 * q + r;
                    int dj = t * 8 + n15 - mp;
                    if (dj >= 0 && dj <= 8 && (t == 0 || n15 >= 8)) {
                        out[base + (size_t)(dio * 9 + dj) * 8192 + mp] = acc[dl][t][r];
                    }
                }
            }
        }
    }
}

extern "C" void kernel_launch(void* const* d_in, const int* in_sizes, int n_in,
                              void* d_out, int out_size, void* d_ws, size_t ws_size,
                              hipStream_t stream) {
    const float* f1 = (const float*)d_in[0];
    const float* f2 = (const float*)d_in[1];
    float* out = (float*)d_out;
    if (ws_size >= WS_NEED && d_ws != nullptr) {
        uint32_t* t2p = (uint32_t*)d_ws;
        transpose_f2<<<dim3(2048), dim3(256), 0, stream>>>(f2, t2p);
        corr2<<<dim3(512), dim3(512), 0, stream>>>(f1, t2p, t2p + T2P_WORDS, out);
    } else {
        corr_kernel<<<dim3(1024), dim3(512), 0, stream>>>(f1, f2, out);
    }
}